// Round 4
// baseline (786.069 us; speedup 1.0000x reference)
//
#include <hip/hip_runtime.h>
#include <hip/hip_fp16.h>
#include <math.h>

#define N_NODES 50000
#define N_EDGES 1600000
#define N_GRAPHS 512
#define F_IN 9
#define H 64

// ---------- CSR build ----------
__global__ void hist_kernel(const int* __restrict__ ei, int* __restrict__ deg) {
    int t = blockIdx.x * blockDim.x + threadIdx.x;
    if (t >= N_EDGES / 4) return;
    int4 d4 = ((const int4*)(ei + N_EDGES))[t];
    atomicAdd(&deg[d4.x], 1);
    atomicAdd(&deg[d4.y], 1);
    atomicAdd(&deg[d4.z], 1);
    atomicAdd(&deg[d4.w], 1);
}

// single-block exclusive scan over deg[N_NODES] -> starts, next (copy)
__global__ void scan_kernel(const int* __restrict__ deg,
                            int* __restrict__ starts,
                            int* __restrict__ next) {
    __shared__ int wsum[16];
    __shared__ int woff[16];
    int tid = threadIdx.x, lane = tid & 63, wid = tid >> 6;
    int run = 0;
    for (int base = 0; base < N_NODES; base += 1024) {
        int i = base + tid;
        int v = (i < N_NODES) ? deg[i] : 0;
        int incl = v;
#pragma unroll
        for (int off = 1; off < 64; off <<= 1) {
            int t = __shfl_up(incl, off, 64);
            if (lane >= off) incl += t;
        }
        if (lane == 63) wsum[wid] = incl;
        __syncthreads();
        if (wid == 0) {
            int wv = (lane < 16) ? wsum[lane] : 0;
            int winc = wv;
#pragma unroll
            for (int off = 1; off < 16; off <<= 1) {
                int t = __shfl_up(winc, off, 64);
                if (lane >= off) winc += t;
            }
            if (lane < 16) woff[lane] = winc - wv;  // exclusive
        }
        __syncthreads();
        int excl = run + woff[wid] + (incl - v);
        if (i < N_NODES) { starts[i] = excl; next[i] = excl; }
        run += woff[15] + wsum[15];
        __syncthreads();
    }
}

// pack (src, attr) into one int2 -> one 8B scattered store per edge
__global__ void scatter_kernel(const int* __restrict__ ei,
                               const float* __restrict__ ea,
                               int* __restrict__ next,
                               int2* __restrict__ epay) {
    int e = blockIdx.x * blockDim.x + threadIdx.x;
    if (e >= N_EDGES) return;
    int d = ei[N_EDGES + e];
    int pos = atomicAdd(&next[d], 1);
    epay[pos] = make_int2(ei[e], __float_as_int(ea[e]));
}

// ---------- conv1 fused: aggregation (4 edge-slots x 16 feat-lanes, unroll 2) + MLP ----------
__global__ void conv1_kernel(const float* __restrict__ x,
                             const int* __restrict__ starts,
                             const int* __restrict__ deg,
                             const int2* __restrict__ epay,
                             const float* __restrict__ e1w,
                             const float* __restrict__ e1b,
                             const float* __restrict__ w1a,
                             const float* __restrict__ b1a,
                             const float* __restrict__ w1b,
                             const float* __restrict__ b1b,
                             __half* __restrict__ h1) {
    int n = blockIdx.x * (blockDim.x >> 6) + (threadIdx.x >> 6);
    int lane = threadIdx.x & 63;
    if (n >= N_NODES) return;
    int slot = lane >> 4;    // 0..3
    int f = lane & 15;       // 0..15, f < 9 active
    int s0 = starts[n], dg = deg[n];
    bool act = f < F_IN;
    float wf = act ? e1w[f] : 0.f;
    float bf = act ? e1b[f] : 0.f;
    float acc = 0.f;
    int j = slot;
    for (; j + 4 < dg; j += 8) {   // two edges per slot in flight
        int2 pa = epay[s0 + j];
        int2 pb = epay[s0 + j + 4];
        float xa_ = act ? x[pa.x * F_IN + f] : 0.f;
        float xb_ = act ? x[pb.x * F_IN + f] : 0.f;
        float ma = xa_ + __int_as_float(pa.y) * wf + bf;
        float mb = xb_ + __int_as_float(pb.y) * wf + bf;
        acc += (act ? fmaxf(ma, 0.f) : 0.f) + (act ? fmaxf(mb, 0.f) : 0.f);
    }
    if (j < dg) {
        int2 p = epay[s0 + j];
        float xv = act ? x[p.x * F_IN + f] : 0.f;
        float m = xv + __int_as_float(p.y) * wf + bf;
        acc += act ? fmaxf(m, 0.f) : 0.f;
    }
    acc += __shfl_xor(acc, 16, 64);
    acc += __shfl_xor(acc, 32, 64);
    float xa = (lane < F_IN) ? x[n * F_IN + lane] + acc : 0.f;
    float a1 = b1a[lane];
#pragma unroll
    for (int k = 0; k < F_IN; ++k)
        a1 += __shfl(xa, k, 64) * w1a[lane * F_IN + k];
    float ha = fmaxf(a1, 0.f);
    float a2 = b1b[lane];
#pragma unroll
    for (int k = 0; k < H; ++k)
        a2 += __shfl(ha, k, 64) * w1b[lane * H + k];
    h1[n * H + lane] = __float2half(fmaxf(a2, 0.f));
}

// ---------- conv2 aggregation (fp16 gather, unroll 8) + node MLP + readout ----------
__global__ __launch_bounds__(256, 8)
void agg2_node2_kernel(const __half* __restrict__ h1,
                       const int* __restrict__ starts,
                       const int* __restrict__ deg,
                       const int2* __restrict__ epay,
                       const float* __restrict__ e2w,
                       const float* __restrict__ e2b,
                       const float* __restrict__ w2a,
                       const float* __restrict__ b2a,
                       const float* __restrict__ w2b,
                       const float* __restrict__ b2b,
                       const float* __restrict__ wr1,
                       const float* __restrict__ br1,
                       const float* __restrict__ wr2,
                       const float* __restrict__ br2,
                       const int* __restrict__ term,
                       const float* __restrict__ ccost,
                       const int* __restrict__ batch,
                       float* __restrict__ pi,
                       float* __restrict__ te) {
    int n = blockIdx.x * (blockDim.x >> 6) + (threadIdx.x >> 6);
    int f = threadIdx.x & 63;
    if (n >= N_NODES) return;
    int s0 = starts[n], dg = deg[n];
    const int2* ep = epay + s0;
    float wf = e2w[f], bf = e2b[f];
    float acc = 0.f;
    int j = 0;
    for (; j + 8 <= dg; j += 8) {
        int2 p0 = ep[j    ], p1 = ep[j + 1], p2 = ep[j + 2], p3 = ep[j + 3];
        int2 p4 = ep[j + 4], p5 = ep[j + 5], p6 = ep[j + 6], p7 = ep[j + 7];
        float v0 = __half2float(h1[p0.x * H + f]);
        float v1 = __half2float(h1[p1.x * H + f]);
        float v2 = __half2float(h1[p2.x * H + f]);
        float v3 = __half2float(h1[p3.x * H + f]);
        float v4 = __half2float(h1[p4.x * H + f]);
        float v5 = __half2float(h1[p5.x * H + f]);
        float v6 = __half2float(h1[p6.x * H + f]);
        float v7 = __half2float(h1[p7.x * H + f]);
        acc += fmaxf(v0 + __int_as_float(p0.y) * wf + bf, 0.f)
             + fmaxf(v1 + __int_as_float(p1.y) * wf + bf, 0.f)
             + fmaxf(v2 + __int_as_float(p2.y) * wf + bf, 0.f)
             + fmaxf(v3 + __int_as_float(p3.y) * wf + bf, 0.f)
             + fmaxf(v4 + __int_as_float(p4.y) * wf + bf, 0.f)
             + fmaxf(v5 + __int_as_float(p5.y) * wf + bf, 0.f)
             + fmaxf(v6 + __int_as_float(p6.y) * wf + bf, 0.f)
             + fmaxf(v7 + __int_as_float(p7.y) * wf + bf, 0.f);
    }
    for (; j < dg; ++j) {
        int2 p = ep[j];
        acc += fmaxf(__half2float(h1[p.x * H + f]) + __int_as_float(p.y) * wf + bf, 0.f);
    }
    float h = __half2float(h1[n * H + f]) + acc;
    float a1 = b2a[f];
#pragma unroll
    for (int k = 0; k < H; ++k)
        a1 += __shfl(h, k, 64) * w2a[f * H + k];
    float h2a = fmaxf(a1, 0.f);
    float a2 = b2b[f];
#pragma unroll
    for (int k = 0; k < H; ++k)
        a2 += __shfl(h2a, k, 64) * w2b[f * H + k];
    float h2 = fmaxf(a2, 0.f);
    int fr = f & 31;
    float accr = br1[fr];
#pragma unroll
    for (int k = 0; k < H; ++k)
        accr += __shfl(h2, k, 64) * wr1[fr * H + k];
    float r = fmaxf(accr, 0.f);
    float val = (f < 32) ? r * wr2[fr] : 0.f;
#pragma unroll
    for (int off = 32; off > 0; off >>= 1)
        val += __shfl_xor(val, off, 64);
    if (f == 0) {
        float z = val + br2[0];
        float sig = 1.f / (1.f + expf(-z));
        float p = sig * (1.f - (float)term[n]);
        pi[n] = p;
        atomicAdd(&te[batch[n]], p * ccost[n]);
    }
}

__global__ void final_kernel(const float* __restrict__ pi,
                             const int* __restrict__ batch,
                             const float* __restrict__ Btot,
                             const float* __restrict__ te,
                             float* __restrict__ out) {
    int n = blockIdx.x * blockDim.x + threadIdx.x;
    if (n >= N_NODES) return;
    int b = batch[n];
    float ratio = fminf(Btot[b] / (te[b] + 1e-12f), 1.f);
    out[n] = pi[n] * ratio;
}

extern "C" void kernel_launch(void* const* d_in, const int* in_sizes, int n_in,
                              void* d_out, int out_size, void* d_ws, size_t ws_size,
                              hipStream_t stream) {
    const float* x     = (const float*)d_in[0];
    const int*   ei    = (const int*)d_in[1];
    const float* ea    = (const float*)d_in[2];
    const int*   batch = (const int*)d_in[3];
    const float* Btot  = (const float*)d_in[4];
    const int*   term  = (const int*)d_in[5];
    const float* ccost = (const float*)d_in[6];
    const float* e1w   = (const float*)d_in[7];
    const float* e1b   = (const float*)d_in[8];
    const float* w1a   = (const float*)d_in[9];
    const float* b1a   = (const float*)d_in[10];
    const float* w1b   = (const float*)d_in[11];
    const float* b1b   = (const float*)d_in[12];
    const float* e2w   = (const float*)d_in[13];
    const float* e2b   = (const float*)d_in[14];
    const float* w2a   = (const float*)d_in[15];
    const float* b2a   = (const float*)d_in[16];
    const float* w2b   = (const float*)d_in[17];
    const float* b2b   = (const float*)d_in[18];
    const float* wr1   = (const float*)d_in[19];
    const float* br1   = (const float*)d_in[20];
    const float* wr2   = (const float*)d_in[21];
    const float* br2   = (const float*)d_in[22];

    char* p = (char*)d_ws;
    int*    deg    = (int*)p;    p += sizeof(int)    * N_NODES;   // zeroed
    float*  te     = (float*)p;  p += sizeof(float)  * N_GRAPHS;  // zeroed
    int*    starts = (int*)p;    p += sizeof(int)    * N_NODES;
    int*    next   = (int*)p;    p += sizeof(int)    * N_NODES;
    int2*   epay   = (int2*)p;   p += sizeof(int2)   * (size_t)N_EDGES;
    __half* h1     = (__half*)p; p += sizeof(__half) * (size_t)N_NODES * H;
    float*  pi     = (float*)p;  p += sizeof(float)  * N_NODES;
    float*  out    = (float*)d_out;

    hipMemsetAsync(d_ws, 0, sizeof(int) * N_NODES + sizeof(float) * N_GRAPHS, stream);

    hist_kernel<<<(N_EDGES / 4 + 255) / 256, 256, 0, stream>>>(ei, deg);
    scan_kernel<<<1, 1024, 0, stream>>>(deg, starts, next);
    scatter_kernel<<<(N_EDGES + 255) / 256, 256, 0, stream>>>(ei, ea, next, epay);
    conv1_kernel<<<(N_NODES + 3) / 4, 256, 0, stream>>>(x, starts, deg, epay,
                                                        e1w, e1b, w1a, b1a, w1b, b1b, h1);
    agg2_node2_kernel<<<(N_NODES + 3) / 4, 256, 0, stream>>>(h1, starts, deg, epay,
                                                             e2w, e2b, w2a, b2a, w2b, b2b,
                                                             wr1, br1, wr2, br2,
                                                             term, ccost, batch, pi, te);
    final_kernel<<<(N_NODES + 255) / 256, 256, 0, stream>>>(pi, batch, Btot, te, out);
}

// Round 5
// 717.873 us; speedup vs baseline: 1.0950x; 1.0950x over previous
//
#include <hip/hip_runtime.h>
#include <hip/hip_fp16.h>
#include <math.h>

#define N_NODES 50000
#define N_EDGES 1600000
#define N_GRAPHS 512
#define F_IN 9
#define H 64
#define SCAN_BLOCK 1024
#define N_CHUNKS ((N_NODES + SCAN_BLOCK - 1) / SCAN_BLOCK)   // 49

// ---------- CSR build ----------
__global__ void hist_kernel(const int* __restrict__ ei, int* __restrict__ deg) {
    int t = blockIdx.x * blockDim.x + threadIdx.x;
    if (t >= N_EDGES / 4) return;
    int4 d4 = ((const int4*)(ei + N_EDGES))[t];
    atomicAdd(&deg[d4.x], 1);
    atomicAdd(&deg[d4.y], 1);
    atomicAdd(&deg[d4.z], 1);
    atomicAdd(&deg[d4.w], 1);
}

// hierarchical scan, stage 1: per-block (1024) exclusive scan + block totals
__global__ void scan_local(const int* __restrict__ deg,
                           int* __restrict__ starts,
                           int* __restrict__ csum) {
    __shared__ int wsum[16];
    __shared__ int woff[16];
    int tid = threadIdx.x, lane = tid & 63, wid = tid >> 6;
    int i = blockIdx.x * SCAN_BLOCK + tid;
    int v = (i < N_NODES) ? deg[i] : 0;
    int incl = v;
#pragma unroll
    for (int off = 1; off < 64; off <<= 1) {
        int t = __shfl_up(incl, off, 64);
        if (lane >= off) incl += t;
    }
    if (lane == 63) wsum[wid] = incl;
    __syncthreads();
    if (wid == 0) {
        int wv = (lane < 16) ? wsum[lane] : 0;
        int winc = wv;
#pragma unroll
        for (int off = 1; off < 16; off <<= 1) {
            int t = __shfl_up(winc, off, 64);
            if (lane >= off) winc += t;
        }
        if (lane < 16) woff[lane] = winc - wv;  // exclusive wave offsets
    }
    __syncthreads();
    if (i < N_NODES) starts[i] = woff[wid] + (incl - v);
    if (tid == 0) csum[blockIdx.x] = woff[15] + wsum[15];
}

// stage 2: one wave scans the 49 block totals (exclusive)
__global__ void scan_top(const int* __restrict__ csum, int* __restrict__ coff) {
    int lane = threadIdx.x;
    int v = (lane < N_CHUNKS) ? csum[lane] : 0;
    int incl = v;
#pragma unroll
    for (int off = 1; off < 64; off <<= 1) {
        int t = __shfl_up(incl, off, 64);
        if (lane >= off) incl += t;
    }
    if (lane < N_CHUNKS) coff[lane] = incl - v;
}

// stage 3: add block offsets, produce starts and next
__global__ void scan_add(int* __restrict__ starts, int* __restrict__ next,
                         const int* __restrict__ coff) {
    int i = blockIdx.x * SCAN_BLOCK + threadIdx.x;
    if (i >= N_NODES) return;
    int s = starts[i] + coff[blockIdx.x];
    starts[i] = s;
    next[i] = s;
}

// pack (src, attr) into one int2 -> one 8B scattered store per edge
__global__ void scatter_kernel(const int* __restrict__ ei,
                               const float* __restrict__ ea,
                               int* __restrict__ next,
                               int2* __restrict__ epay) {
    int e = blockIdx.x * blockDim.x + threadIdx.x;
    if (e >= N_EDGES) return;
    int d = ei[N_EDGES + e];
    int pos = atomicAdd(&next[d], 1);
    epay[pos] = make_int2(ei[e], __float_as_int(ea[e]));
}

// ---------- conv1 fused: aggregation (4 edge-slots x 16 feat-lanes, unroll 2) + MLP ----------
__global__ void conv1_kernel(const float* __restrict__ x,
                             const int* __restrict__ starts,
                             const int* __restrict__ deg,
                             const int2* __restrict__ epay,
                             const float* __restrict__ e1w,
                             const float* __restrict__ e1b,
                             const float* __restrict__ w1a,
                             const float* __restrict__ b1a,
                             const float* __restrict__ w1b,
                             const float* __restrict__ b1b,
                             __half* __restrict__ h1) {
    int n = blockIdx.x * (blockDim.x >> 6) + (threadIdx.x >> 6);
    int lane = threadIdx.x & 63;
    if (n >= N_NODES) return;
    int slot = lane >> 4;    // 0..3
    int f = lane & 15;       // 0..15, f < 9 active
    int s0 = starts[n], dg = deg[n];
    bool act = f < F_IN;
    float wf = act ? e1w[f] : 0.f;
    float bf = act ? e1b[f] : 0.f;
    float acc = 0.f;
    int j = slot;
    for (; j + 4 < dg; j += 8) {   // two edges per slot in flight
        int2 pa = epay[s0 + j];
        int2 pb = epay[s0 + j + 4];
        float xa_ = act ? x[pa.x * F_IN + f] : 0.f;
        float xb_ = act ? x[pb.x * F_IN + f] : 0.f;
        float ma = xa_ + __int_as_float(pa.y) * wf + bf;
        float mb = xb_ + __int_as_float(pb.y) * wf + bf;
        acc += (act ? fmaxf(ma, 0.f) : 0.f) + (act ? fmaxf(mb, 0.f) : 0.f);
    }
    if (j < dg) {
        int2 p = epay[s0 + j];
        float xv = act ? x[p.x * F_IN + f] : 0.f;
        float m = xv + __int_as_float(p.y) * wf + bf;
        acc += act ? fmaxf(m, 0.f) : 0.f;
    }
    acc += __shfl_xor(acc, 16, 64);
    acc += __shfl_xor(acc, 32, 64);
    float xa = (lane < F_IN) ? x[n * F_IN + lane] + acc : 0.f;
    float a1 = b1a[lane];
#pragma unroll
    for (int k = 0; k < F_IN; ++k)
        a1 += __shfl(xa, k, 64) * w1a[lane * F_IN + k];
    float ha = fmaxf(a1, 0.f);
    float a2 = b1b[lane];
#pragma unroll
    for (int k = 0; k < H; ++k)
        a2 += __shfl(ha, k, 64) * w1b[lane * H + k];
    h1[n * H + lane] = __float2half(fmaxf(a2, 0.f));
}

// ---------- conv2 aggregation (half2 gather: 2 edges per wave-load, 8 in flight
//            -> 16 edges per unroll) + node MLP + readout ----------
__global__ void agg2_node2_kernel(const __half* __restrict__ h1,
                                  const int* __restrict__ starts,
                                  const int* __restrict__ deg,
                                  const int2* __restrict__ epay,
                                  const float* __restrict__ e2w,
                                  const float* __restrict__ e2b,
                                  const float* __restrict__ w2a,
                                  const float* __restrict__ b2a,
                                  const float* __restrict__ w2b,
                                  const float* __restrict__ b2b,
                                  const float* __restrict__ wr1,
                                  const float* __restrict__ br1,
                                  const float* __restrict__ wr2,
                                  const float* __restrict__ br2,
                                  const int* __restrict__ term,
                                  const float* __restrict__ ccost,
                                  const int* __restrict__ batch,
                                  float* __restrict__ pi,
                                  float* __restrict__ te) {
    int n = blockIdx.x * (blockDim.x >> 6) + (threadIdx.x >> 6);
    int f = threadIdx.x & 63;
    if (n >= N_NODES) return;
    int half = f >> 5;       // 0: edge j, 1: edge j+1
    int fh = f & 31;         // feature pair index: features 2fh, 2fh+1
    int s0 = starts[n], dg = deg[n];
    const int2* ep = epay + s0;
    float wfx = e2w[2 * fh], wfy = e2w[2 * fh + 1];
    float bfx = e2b[2 * fh], bfy = e2b[2 * fh + 1];
    float accx = 0.f, accy = 0.f;
    int j = 0;
#define EDGE2(P, V) do {                                                   \
        float a_ = __int_as_float((P).y);                                  \
        float2 v_ = __half22float2(V);                                     \
        accx += fmaxf(v_.x + a_ * wfx + bfx, 0.f);                         \
        accy += fmaxf(v_.y + a_ * wfy + bfy, 0.f);                         \
    } while (0)
    for (; j + 16 <= dg; j += 16) {
        int2 p0 = ep[j +  0 + half], p1 = ep[j +  2 + half];
        int2 p2 = ep[j +  4 + half], p3 = ep[j +  6 + half];
        int2 p4 = ep[j +  8 + half], p5 = ep[j + 10 + half];
        int2 p6 = ep[j + 12 + half], p7 = ep[j + 14 + half];
        __half2 v0 = *(const __half2*)(h1 + p0.x * H + 2 * fh);
        __half2 v1 = *(const __half2*)(h1 + p1.x * H + 2 * fh);
        __half2 v2 = *(const __half2*)(h1 + p2.x * H + 2 * fh);
        __half2 v3 = *(const __half2*)(h1 + p3.x * H + 2 * fh);
        __half2 v4 = *(const __half2*)(h1 + p4.x * H + 2 * fh);
        __half2 v5 = *(const __half2*)(h1 + p5.x * H + 2 * fh);
        __half2 v6 = *(const __half2*)(h1 + p6.x * H + 2 * fh);
        __half2 v7 = *(const __half2*)(h1 + p7.x * H + 2 * fh);
        EDGE2(p0, v0); EDGE2(p1, v1); EDGE2(p2, v2); EDGE2(p3, v3);
        EDGE2(p4, v4); EDGE2(p5, v5); EDGE2(p6, v6); EDGE2(p7, v7);
    }
    for (; j + 2 <= dg; j += 2) {
        int2 p = ep[j + half];
        __half2 v = *(const __half2*)(h1 + p.x * H + 2 * fh);
        EDGE2(p, v);
    }
    if (j < dg && half == 0) {   // odd leftover edge: lanes 0..31 only
        int2 p = ep[j];
        __half2 v = *(const __half2*)(h1 + p.x * H + 2 * fh);
        EDGE2(p, v);
    }
#undef EDGE2
    // combine the two edge-halves; then every lane fetches its feature's sum
    accx += __shfl_xor(accx, 32, 64);
    accy += __shfl_xor(accy, 32, 64);
    float ax = __shfl(accx, f >> 1, 64);
    float ay = __shfl(accy, f >> 1, 64);
    float aggf = (f & 1) ? ay : ax;
    float h = __half2float(h1[n * H + f]) + aggf;
    float a1 = b2a[f];
#pragma unroll
    for (int k = 0; k < H; ++k)
        a1 += __shfl(h, k, 64) * w2a[f * H + k];
    float h2a = fmaxf(a1, 0.f);
    float a2 = b2b[f];
#pragma unroll
    for (int k = 0; k < H; ++k)
        a2 += __shfl(h2a, k, 64) * w2b[f * H + k];
    float h2 = fmaxf(a2, 0.f);
    int fr = f & 31;
    float accr = br1[fr];
#pragma unroll
    for (int k = 0; k < H; ++k)
        accr += __shfl(h2, k, 64) * wr1[fr * H + k];
    float r = fmaxf(accr, 0.f);
    float val = (f < 32) ? r * wr2[fr] : 0.f;
#pragma unroll
    for (int off = 32; off > 0; off >>= 1)
        val += __shfl_xor(val, off, 64);
    if (f == 0) {
        float z = val + br2[0];
        float sig = 1.f / (1.f + expf(-z));
        float p = sig * (1.f - (float)term[n]);
        pi[n] = p;
        atomicAdd(&te[batch[n]], p * ccost[n]);
    }
}

__global__ void final_kernel(const float* __restrict__ pi,
                             const int* __restrict__ batch,
                             const float* __restrict__ Btot,
                             const float* __restrict__ te,
                             float* __restrict__ out) {
    int n = blockIdx.x * blockDim.x + threadIdx.x;
    if (n >= N_NODES) return;
    int b = batch[n];
    float ratio = fminf(Btot[b] / (te[b] + 1e-12f), 1.f);
    out[n] = pi[n] * ratio;
}

extern "C" void kernel_launch(void* const* d_in, const int* in_sizes, int n_in,
                              void* d_out, int out_size, void* d_ws, size_t ws_size,
                              hipStream_t stream) {
    const float* x     = (const float*)d_in[0];
    const int*   ei    = (const int*)d_in[1];
    const float* ea    = (const float*)d_in[2];
    const int*   batch = (const int*)d_in[3];
    const float* Btot  = (const float*)d_in[4];
    const int*   term  = (const int*)d_in[5];
    const float* ccost = (const float*)d_in[6];
    const float* e1w   = (const float*)d_in[7];
    const float* e1b   = (const float*)d_in[8];
    const float* w1a   = (const float*)d_in[9];
    const float* b1a   = (const float*)d_in[10];
    const float* w1b   = (const float*)d_in[11];
    const float* b1b   = (const float*)d_in[12];
    const float* e2w   = (const float*)d_in[13];
    const float* e2b   = (const float*)d_in[14];
    const float* w2a   = (const float*)d_in[15];
    const float* b2a   = (const float*)d_in[16];
    const float* w2b   = (const float*)d_in[17];
    const float* b2b   = (const float*)d_in[18];
    const float* wr1   = (const float*)d_in[19];
    const float* br1   = (const float*)d_in[20];
    const float* wr2   = (const float*)d_in[21];
    const float* br2   = (const float*)d_in[22];

    char* p = (char*)d_ws;
    int*    deg    = (int*)p;    p += sizeof(int)    * N_NODES;   // zeroed
    float*  te     = (float*)p;  p += sizeof(float)  * N_GRAPHS;  // zeroed
    int*    starts = (int*)p;    p += sizeof(int)    * N_NODES;
    int*    next   = (int*)p;    p += sizeof(int)    * N_NODES;
    int*    csum   = (int*)p;    p += sizeof(int)    * 64;
    int*    coff   = (int*)p;    p += sizeof(int)    * 64;
    int2*   epay   = (int2*)p;   p += sizeof(int2)   * (size_t)N_EDGES;
    __half* h1     = (__half*)p; p += sizeof(__half) * (size_t)N_NODES * H;
    float*  pi     = (float*)p;  p += sizeof(float)  * N_NODES;
    float*  out    = (float*)d_out;

    hipMemsetAsync(d_ws, 0, sizeof(int) * N_NODES + sizeof(float) * N_GRAPHS, stream);

    hist_kernel<<<(N_EDGES / 4 + 255) / 256, 256, 0, stream>>>(ei, deg);
    scan_local<<<N_CHUNKS, SCAN_BLOCK, 0, stream>>>(deg, starts, csum);
    scan_top<<<1, 64, 0, stream>>>(csum, coff);
    scan_add<<<N_CHUNKS, SCAN_BLOCK, 0, stream>>>(starts, next, coff);
    scatter_kernel<<<(N_EDGES + 255) / 256, 256, 0, stream>>>(ei, ea, next, epay);
    conv1_kernel<<<(N_NODES + 3) / 4, 256, 0, stream>>>(x, starts, deg, epay,
                                                        e1w, e1b, w1a, b1a, w1b, b1b, h1);
    agg2_node2_kernel<<<(N_NODES + 3) / 4, 256, 0, stream>>>(h1, starts, deg, epay,
                                                             e2w, e2b, w2a, b2a, w2b, b2b,
                                                             wr1, br1, wr2, br2,
                                                             term, ccost, batch, pi, te);
    final_kernel<<<(N_NODES + 255) / 256, 256, 0, stream>>>(pi, batch, Btot, te, out);
}

// Round 6
// 544.889 us; speedup vs baseline: 1.4426x; 1.3175x over previous
//
#include <hip/hip_runtime.h>
#include <hip/hip_fp16.h>
#include <math.h>

#define N_NODES 50000
#define N_EDGES 1600000
#define N_GRAPHS 512
#define F_IN 9
#define H 64
#define SCAN_BLOCK 1024
#define N_CHUNKS ((N_NODES + SCAN_BLOCK - 1) / SCAN_BLOCK)   // 49

// ---------- weight transpose: wT[k][f] = w[f][k], so MLP loop iteration k
// reads 64 CONSECUTIVE floats (4 cache lines) instead of 64 scattered rows ----------
__global__ void transpose_weights(const float* __restrict__ w1a,
                                  const float* __restrict__ w1b,
                                  const float* __restrict__ w2a,
                                  const float* __restrict__ w2b,
                                  const float* __restrict__ wr1,
                                  float* __restrict__ w1aT,
                                  float* __restrict__ w1bT,
                                  float* __restrict__ w2aT,
                                  float* __restrict__ w2bT,
                                  float* __restrict__ wr1T) {
    int t = threadIdx.x;
    for (int i = t; i < H * F_IN; i += 256) {          // w1a: [64][9] -> [9][64]
        int f = i / F_IN, k = i % F_IN;
        w1aT[k * H + f] = w1a[i];
    }
    for (int i = t; i < H * H; i += 256) {             // w1b: [64][64] -> [64][64]
        int f = i / H, k = i % H;
        w1bT[k * H + f] = w1b[i];
    }
    for (int i = t; i < H * H; i += 256) {
        int f = i / H, k = i % H;
        w2aT[k * H + f] = w2a[i];
    }
    for (int i = t; i < H * H; i += 256) {
        int f = i / H, k = i % H;
        w2bT[k * H + f] = w2b[i];
    }
    for (int i = t; i < 32 * H; i += 256) {            // wr1: [32][64] -> [64][32]
        int f = i / H, k = i % H;
        wr1T[k * 32 + f] = wr1[i];
    }
}

// ---------- CSR build ----------
__global__ void hist_kernel(const int* __restrict__ ei, int* __restrict__ deg) {
    int t = blockIdx.x * blockDim.x + threadIdx.x;
    if (t >= N_EDGES / 4) return;
    int4 d4 = ((const int4*)(ei + N_EDGES))[t];
    atomicAdd(&deg[d4.x], 1);
    atomicAdd(&deg[d4.y], 1);
    atomicAdd(&deg[d4.z], 1);
    atomicAdd(&deg[d4.w], 1);
}

__global__ void scan_local(const int* __restrict__ deg,
                           int* __restrict__ starts,
                           int* __restrict__ csum) {
    __shared__ int wsum[16];
    __shared__ int woff[16];
    int tid = threadIdx.x, lane = tid & 63, wid = tid >> 6;
    int i = blockIdx.x * SCAN_BLOCK + tid;
    int v = (i < N_NODES) ? deg[i] : 0;
    int incl = v;
#pragma unroll
    for (int off = 1; off < 64; off <<= 1) {
        int t = __shfl_up(incl, off, 64);
        if (lane >= off) incl += t;
    }
    if (lane == 63) wsum[wid] = incl;
    __syncthreads();
    if (wid == 0) {
        int wv = (lane < 16) ? wsum[lane] : 0;
        int winc = wv;
#pragma unroll
        for (int off = 1; off < 16; off <<= 1) {
            int t = __shfl_up(winc, off, 64);
            if (lane >= off) winc += t;
        }
        if (lane < 16) woff[lane] = winc - wv;
    }
    __syncthreads();
    if (i < N_NODES) starts[i] = woff[wid] + (incl - v);
    if (tid == 0) csum[blockIdx.x] = woff[15] + wsum[15];
}

__global__ void scan_top(const int* __restrict__ csum, int* __restrict__ coff) {
    int lane = threadIdx.x;
    int v = (lane < N_CHUNKS) ? csum[lane] : 0;
    int incl = v;
#pragma unroll
    for (int off = 1; off < 64; off <<= 1) {
        int t = __shfl_up(incl, off, 64);
        if (lane >= off) incl += t;
    }
    if (lane < N_CHUNKS) coff[lane] = incl - v;
}

__global__ void scan_add(int* __restrict__ starts, int* __restrict__ next,
                         const int* __restrict__ coff) {
    int i = blockIdx.x * SCAN_BLOCK + threadIdx.x;
    if (i >= N_NODES) return;
    int s = starts[i] + coff[blockIdx.x];
    starts[i] = s;
    next[i] = s;
}

__global__ void scatter_kernel(const int* __restrict__ ei,
                               const float* __restrict__ ea,
                               int* __restrict__ next,
                               int2* __restrict__ epay) {
    int e = blockIdx.x * blockDim.x + threadIdx.x;
    if (e >= N_EDGES) return;
    int d = ei[N_EDGES + e];
    int pos = atomicAdd(&next[d], 1);
    epay[pos] = make_int2(ei[e], __float_as_int(ea[e]));
}

// ---------- conv1 fused: aggregation + MLP (transposed weights) ----------
__global__ void conv1_kernel(const float* __restrict__ x,
                             const int* __restrict__ starts,
                             const int* __restrict__ deg,
                             const int2* __restrict__ epay,
                             const float* __restrict__ e1w,
                             const float* __restrict__ e1b,
                             const float* __restrict__ w1aT,
                             const float* __restrict__ b1a,
                             const float* __restrict__ w1bT,
                             const float* __restrict__ b1b,
                             __half* __restrict__ h1) {
    int n = blockIdx.x * (blockDim.x >> 6) + (threadIdx.x >> 6);
    int lane = threadIdx.x & 63;
    if (n >= N_NODES) return;
    int slot = lane >> 4;
    int f = lane & 15;
    int s0 = starts[n], dg = deg[n];
    bool act = f < F_IN;
    float wf = act ? e1w[f] : 0.f;
    float bf = act ? e1b[f] : 0.f;
    float acc = 0.f;
    int j = slot;
    for (; j + 4 < dg; j += 8) {
        int2 pa = epay[s0 + j];
        int2 pb = epay[s0 + j + 4];
        float xa_ = act ? x[pa.x * F_IN + f] : 0.f;
        float xb_ = act ? x[pb.x * F_IN + f] : 0.f;
        float ma = xa_ + __int_as_float(pa.y) * wf + bf;
        float mb = xb_ + __int_as_float(pb.y) * wf + bf;
        acc += (act ? fmaxf(ma, 0.f) : 0.f) + (act ? fmaxf(mb, 0.f) : 0.f);
    }
    if (j < dg) {
        int2 p = epay[s0 + j];
        float xv = act ? x[p.x * F_IN + f] : 0.f;
        float m = xv + __int_as_float(p.y) * wf + bf;
        acc += act ? fmaxf(m, 0.f) : 0.f;
    }
    acc += __shfl_xor(acc, 16, 64);
    acc += __shfl_xor(acc, 32, 64);
    float xa = (lane < F_IN) ? x[n * F_IN + lane] + acc : 0.f;
    float a1 = b1a[lane];
#pragma unroll
    for (int k = 0; k < F_IN; ++k)
        a1 += __shfl(xa, k, 64) * w1aT[k * H + lane];   // coalesced: 256B / iter
    float ha = fmaxf(a1, 0.f);
    float a2 = b1b[lane];
#pragma unroll 16
    for (int k = 0; k < H; ++k)
        a2 += __shfl(ha, k, 64) * w1bT[k * H + lane];   // coalesced
    h1[n * H + lane] = __float2half(fmaxf(a2, 0.f));
}

// ---------- conv2 aggregation (half2, 16-edge unroll) + MLP (transposed wts) + readout ----------
__global__ void agg2_node2_kernel(const __half* __restrict__ h1,
                                  const int* __restrict__ starts,
                                  const int* __restrict__ deg,
                                  const int2* __restrict__ epay,
                                  const float* __restrict__ e2w,
                                  const float* __restrict__ e2b,
                                  const float* __restrict__ w2aT,
                                  const float* __restrict__ b2a,
                                  const float* __restrict__ w2bT,
                                  const float* __restrict__ b2b,
                                  const float* __restrict__ wr1T,
                                  const float* __restrict__ br1,
                                  const float* __restrict__ wr2,
                                  const float* __restrict__ br2,
                                  const int* __restrict__ term,
                                  const float* __restrict__ ccost,
                                  const int* __restrict__ batch,
                                  float* __restrict__ pi,
                                  float* __restrict__ te) {
    int n = blockIdx.x * (blockDim.x >> 6) + (threadIdx.x >> 6);
    int f = threadIdx.x & 63;
    if (n >= N_NODES) return;
    int half = f >> 5;
    int fh = f & 31;
    int s0 = starts[n], dg = deg[n];
    const int2* ep = epay + s0;
    float wfx = e2w[2 * fh], wfy = e2w[2 * fh + 1];
    float bfx = e2b[2 * fh], bfy = e2b[2 * fh + 1];
    float accx = 0.f, accy = 0.f;
    int j = 0;
#define EDGE2(P, V) do {                                                   \
        float a_ = __int_as_float((P).y);                                  \
        float2 v_ = __half22float2(V);                                     \
        accx += fmaxf(v_.x + a_ * wfx + bfx, 0.f);                         \
        accy += fmaxf(v_.y + a_ * wfy + bfy, 0.f);                         \
    } while (0)
    for (; j + 16 <= dg; j += 16) {
        int2 p0 = ep[j +  0 + half], p1 = ep[j +  2 + half];
        int2 p2 = ep[j +  4 + half], p3 = ep[j +  6 + half];
        int2 p4 = ep[j +  8 + half], p5 = ep[j + 10 + half];
        int2 p6 = ep[j + 12 + half], p7 = ep[j + 14 + half];
        __half2 v0 = *(const __half2*)(h1 + p0.x * H + 2 * fh);
        __half2 v1 = *(const __half2*)(h1 + p1.x * H + 2 * fh);
        __half2 v2 = *(const __half2*)(h1 + p2.x * H + 2 * fh);
        __half2 v3 = *(const __half2*)(h1 + p3.x * H + 2 * fh);
        __half2 v4 = *(const __half2*)(h1 + p4.x * H + 2 * fh);
        __half2 v5 = *(const __half2*)(h1 + p5.x * H + 2 * fh);
        __half2 v6 = *(const __half2*)(h1 + p6.x * H + 2 * fh);
        __half2 v7 = *(const __half2*)(h1 + p7.x * H + 2 * fh);
        EDGE2(p0, v0); EDGE2(p1, v1); EDGE2(p2, v2); EDGE2(p3, v3);
        EDGE2(p4, v4); EDGE2(p5, v5); EDGE2(p6, v6); EDGE2(p7, v7);
    }
    for (; j + 2 <= dg; j += 2) {
        int2 p = ep[j + half];
        __half2 v = *(const __half2*)(h1 + p.x * H + 2 * fh);
        EDGE2(p, v);
    }
    if (j < dg && half == 0) {
        int2 p = ep[j];
        __half2 v = *(const __half2*)(h1 + p.x * H + 2 * fh);
        EDGE2(p, v);
    }
#undef EDGE2
    accx += __shfl_xor(accx, 32, 64);
    accy += __shfl_xor(accy, 32, 64);
    float ax = __shfl(accx, f >> 1, 64);
    float ay = __shfl(accy, f >> 1, 64);
    float aggf = (f & 1) ? ay : ax;
    float h = __half2float(h1[n * H + f]) + aggf;
    float a1 = b2a[f];
#pragma unroll 16
    for (int k = 0; k < H; ++k)
        a1 += __shfl(h, k, 64) * w2aT[k * H + f];       // coalesced: 256B / iter
    float h2a = fmaxf(a1, 0.f);
    float a2 = b2b[f];
#pragma unroll 16
    for (int k = 0; k < H; ++k)
        a2 += __shfl(h2a, k, 64) * w2bT[k * H + f];     // coalesced
    float h2 = fmaxf(a2, 0.f);
    int fr = f & 31;
    float accr = br1[fr];
#pragma unroll 16
    for (int k = 0; k < H; ++k)
        accr += __shfl(h2, k, 64) * wr1T[k * 32 + fr];  // 2 lines / iter
    float r = fmaxf(accr, 0.f);
    float val = (f < 32) ? r * wr2[fr] : 0.f;
#pragma unroll
    for (int off = 32; off > 0; off >>= 1)
        val += __shfl_xor(val, off, 64);
    if (f == 0) {
        float z = val + br2[0];
        float sig = 1.f / (1.f + expf(-z));
        float p = sig * (1.f - (float)term[n]);
        pi[n] = p;
        atomicAdd(&te[batch[n]], p * ccost[n]);
    }
}

__global__ void final_kernel(const float* __restrict__ pi,
                             const int* __restrict__ batch,
                             const float* __restrict__ Btot,
                             const float* __restrict__ te,
                             float* __restrict__ out) {
    int n = blockIdx.x * blockDim.x + threadIdx.x;
    if (n >= N_NODES) return;
    int b = batch[n];
    float ratio = fminf(Btot[b] / (te[b] + 1e-12f), 1.f);
    out[n] = pi[n] * ratio;
}

extern "C" void kernel_launch(void* const* d_in, const int* in_sizes, int n_in,
                              void* d_out, int out_size, void* d_ws, size_t ws_size,
                              hipStream_t stream) {
    const float* x     = (const float*)d_in[0];
    const int*   ei    = (const int*)d_in[1];
    const float* ea    = (const float*)d_in[2];
    const int*   batch = (const int*)d_in[3];
    const float* Btot  = (const float*)d_in[4];
    const int*   term  = (const int*)d_in[5];
    const float* ccost = (const float*)d_in[6];
    const float* e1w   = (const float*)d_in[7];
    const float* e1b   = (const float*)d_in[8];
    const float* w1a   = (const float*)d_in[9];
    const float* b1a   = (const float*)d_in[10];
    const float* w1b   = (const float*)d_in[11];
    const float* b1b   = (const float*)d_in[12];
    const float* e2w   = (const float*)d_in[13];
    const float* e2b   = (const float*)d_in[14];
    const float* w2a   = (const float*)d_in[15];
    const float* b2a   = (const float*)d_in[16];
    const float* w2b   = (const float*)d_in[17];
    const float* b2b   = (const float*)d_in[18];
    const float* wr1   = (const float*)d_in[19];
    const float* br1   = (const float*)d_in[20];
    const float* wr2   = (const float*)d_in[21];
    const float* br2   = (const float*)d_in[22];

    char* p = (char*)d_ws;
    int*    deg    = (int*)p;    p += sizeof(int)    * N_NODES;   // zeroed
    float*  te     = (float*)p;  p += sizeof(float)  * N_GRAPHS;  // zeroed
    int*    starts = (int*)p;    p += sizeof(int)    * N_NODES;
    int*    next   = (int*)p;    p += sizeof(int)    * N_NODES;
    int*    csum   = (int*)p;    p += sizeof(int)    * 64;
    int*    coff   = (int*)p;    p += sizeof(int)    * 64;
    int2*   epay   = (int2*)p;   p += sizeof(int2)   * (size_t)N_EDGES;
    __half* h1     = (__half*)p; p += sizeof(__half) * (size_t)N_NODES * H;
    float*  pi     = (float*)p;  p += sizeof(float)  * N_NODES;
    float*  w1aT   = (float*)p;  p += sizeof(float)  * F_IN * H;
    float*  w1bT   = (float*)p;  p += sizeof(float)  * H * H;
    float*  w2aT   = (float*)p;  p += sizeof(float)  * H * H;
    float*  w2bT   = (float*)p;  p += sizeof(float)  * H * H;
    float*  wr1T   = (float*)p;  p += sizeof(float)  * H * 32;
    float*  out    = (float*)d_out;

    hipMemsetAsync(d_ws, 0, sizeof(int) * N_NODES + sizeof(float) * N_GRAPHS, stream);

    transpose_weights<<<1, 256, 0, stream>>>(w1a, w1b, w2a, w2b, wr1,
                                             w1aT, w1bT, w2aT, w2bT, wr1T);
    hist_kernel<<<(N_EDGES / 4 + 255) / 256, 256, 0, stream>>>(ei, deg);
    scan_local<<<N_CHUNKS, SCAN_BLOCK, 0, stream>>>(deg, starts, csum);
    scan_top<<<1, 64, 0, stream>>>(csum, coff);
    scan_add<<<N_CHUNKS, SCAN_BLOCK, 0, stream>>>(starts, next, coff);
    scatter_kernel<<<(N_EDGES + 255) / 256, 256, 0, stream>>>(ei, ea, next, epay);
    conv1_kernel<<<(N_NODES + 3) / 4, 256, 0, stream>>>(x, starts, deg, epay,
                                                        e1w, e1b, w1aT, b1a, w1bT, b1b, h1);
    agg2_node2_kernel<<<(N_NODES + 3) / 4, 256, 0, stream>>>(h1, starts, deg, epay,
                                                             e2w, e2b, w2aT, b2a, w2bT, b2b,
                                                             wr1T, br1, wr2, br2,
                                                             term, ccost, batch, pi, te);
    final_kernel<<<(N_NODES + 255) / 256, 256, 0, stream>>>(pi, batch, Btot, te, out);
}

// Round 7
// 532.710 us; speedup vs baseline: 1.4756x; 1.0229x over previous
//
#include <hip/hip_runtime.h>
#include <hip/hip_fp16.h>
#include <math.h>

#define N_NODES 50000
#define N_EDGES 1600000
#define N_GRAPHS 512
#define F_IN 9
#define H 64
#define SCAN_BLOCK 1024
#define N_CHUNKS ((N_NODES + SCAN_BLOCK - 1) / SCAN_BLOCK)   // 49

// ---------- prep: block 0 transposes weights, blocks >=1 histogram dst ----------
__global__ void prep_kernel(const int* __restrict__ ei, int* __restrict__ deg,
                            const float* __restrict__ w1a,
                            const float* __restrict__ w1b,
                            const float* __restrict__ w2a,
                            const float* __restrict__ w2b,
                            const float* __restrict__ wr1,
                            float* __restrict__ w1aT,
                            float* __restrict__ w1bT,
                            float* __restrict__ w2aT,
                            float* __restrict__ w2bT,
                            float* __restrict__ wr1T) {
    if (blockIdx.x == 0) {
        int t = threadIdx.x;
        for (int i = t; i < H * F_IN; i += 256) {
            int f = i / F_IN, k = i % F_IN;
            w1aT[k * H + f] = w1a[i];
        }
        for (int i = t; i < H * H; i += 256) {
            int f = i / H, k = i % H;
            w1bT[k * H + f] = w1b[i];
            w2aT[k * H + f] = w2a[i];
            w2bT[k * H + f] = w2b[i];
        }
        for (int i = t; i < 32 * H; i += 256) {
            int f = i / H, k = i % H;
            wr1T[k * 32 + f] = wr1[i];
        }
        return;
    }
    int t = (blockIdx.x - 1) * blockDim.x + threadIdx.x;
    if (t >= N_EDGES / 4) return;
    int4 d4 = ((const int4*)(ei + N_EDGES))[t];
    atomicAdd(&deg[d4.x], 1);
    atomicAdd(&deg[d4.y], 1);
    atomicAdd(&deg[d4.z], 1);
    atomicAdd(&deg[d4.w], 1);
}

__global__ void scan_local(const int* __restrict__ deg,
                           int* __restrict__ starts,
                           int* __restrict__ csum) {
    __shared__ int wsum[16];
    __shared__ int woff[16];
    int tid = threadIdx.x, lane = tid & 63, wid = tid >> 6;
    int i = blockIdx.x * SCAN_BLOCK + tid;
    int v = (i < N_NODES) ? deg[i] : 0;
    int incl = v;
#pragma unroll
    for (int off = 1; off < 64; off <<= 1) {
        int t = __shfl_up(incl, off, 64);
        if (lane >= off) incl += t;
    }
    if (lane == 63) wsum[wid] = incl;
    __syncthreads();
    if (wid == 0) {
        int wv = (lane < 16) ? wsum[lane] : 0;
        int winc = wv;
#pragma unroll
        for (int off = 1; off < 16; off <<= 1) {
            int t = __shfl_up(winc, off, 64);
            if (lane >= off) winc += t;
        }
        if (lane < 16) woff[lane] = winc - wv;
    }
    __syncthreads();
    if (i < N_NODES) starts[i] = woff[wid] + (incl - v);
    if (tid == 0) csum[blockIdx.x] = woff[15] + wsum[15];
}

__global__ void scan_top(const int* __restrict__ csum, int* __restrict__ coff) {
    int lane = threadIdx.x;
    int v = (lane < N_CHUNKS) ? csum[lane] : 0;
    int incl = v;
#pragma unroll
    for (int off = 1; off < 64; off <<= 1) {
        int t = __shfl_up(incl, off, 64);
        if (lane >= off) incl += t;
    }
    if (lane < N_CHUNKS) coff[lane] = incl - v;
}

__global__ void scan_add(int* __restrict__ starts, int* __restrict__ next,
                         const int* __restrict__ coff) {
    int i = blockIdx.x * SCAN_BLOCK + threadIdx.x;
    if (i >= N_NODES) return;
    int s = starts[i] + coff[blockIdx.x];
    starts[i] = s;
    next[i] = s;
}

__global__ void scatter_kernel(const int* __restrict__ ei,
                               const float* __restrict__ ea,
                               int* __restrict__ next,
                               int2* __restrict__ epay) {
    int e = blockIdx.x * blockDim.x + threadIdx.x;
    if (e >= N_EDGES) return;
    int d = ei[N_EDGES + e];
    int pos = atomicAdd(&next[d], 1);
    epay[pos] = make_int2(ei[e], __float_as_int(ea[e]));
}

// ---------- conv1 fused: aggregation (4 slots x 16 lanes, unroll 4 -> 16 edges in flight) + MLP ----------
__global__ void conv1_kernel(const float* __restrict__ x,
                             const int* __restrict__ starts,
                             const int* __restrict__ deg,
                             const int2* __restrict__ epay,
                             const float* __restrict__ e1w,
                             const float* __restrict__ e1b,
                             const float* __restrict__ w1aT,
                             const float* __restrict__ b1a,
                             const float* __restrict__ w1bT,
                             const float* __restrict__ b1b,
                             __half* __restrict__ h1) {
    int n = blockIdx.x * (blockDim.x >> 6) + (threadIdx.x >> 6);
    int lane = threadIdx.x & 63;
    if (n >= N_NODES) return;
    int slot = lane >> 4;
    int f = lane & 15;
    int s0 = starts[n], dg = deg[n];
    bool act = f < F_IN;
    float wf = act ? e1w[f] : 0.f;
    float bf = act ? e1b[f] : 0.f;
    float acc = 0.f;
    int j = slot;
    for (; j + 12 < dg; j += 16) {      // 4 edges per slot in flight (16/wave)
        int2 pa = epay[s0 + j];
        int2 pb = epay[s0 + j + 4];
        int2 pc = epay[s0 + j + 8];
        int2 pd = epay[s0 + j + 12];
        float xa_ = act ? x[pa.x * F_IN + f] : 0.f;
        float xb_ = act ? x[pb.x * F_IN + f] : 0.f;
        float xc_ = act ? x[pc.x * F_IN + f] : 0.f;
        float xd_ = act ? x[pd.x * F_IN + f] : 0.f;
        if (act) {
            acc += fmaxf(xa_ + __int_as_float(pa.y) * wf + bf, 0.f)
                 + fmaxf(xb_ + __int_as_float(pb.y) * wf + bf, 0.f)
                 + fmaxf(xc_ + __int_as_float(pc.y) * wf + bf, 0.f)
                 + fmaxf(xd_ + __int_as_float(pd.y) * wf + bf, 0.f);
        }
    }
    for (; j < dg; j += 4) {
        int2 p = epay[s0 + j];
        float xv = act ? x[p.x * F_IN + f] : 0.f;
        float m = xv + __int_as_float(p.y) * wf + bf;
        acc += act ? fmaxf(m, 0.f) : 0.f;
    }
    acc += __shfl_xor(acc, 16, 64);
    acc += __shfl_xor(acc, 32, 64);
    float xa = (lane < F_IN) ? x[n * F_IN + lane] + acc : 0.f;
    float a1 = b1a[lane];
#pragma unroll
    for (int k = 0; k < F_IN; ++k)
        a1 += __shfl(xa, k, 64) * w1aT[k * H + lane];
    float ha = fmaxf(a1, 0.f);
    float a2 = b1b[lane];
#pragma unroll 16
    for (int k = 0; k < H; ++k)
        a2 += __shfl(ha, k, 64) * w1bT[k * H + lane];
    h1[n * H + lane] = __float2half(fmaxf(a2, 0.f));
}

// ---------- conv2: 4 edges per wave-gather (8B/lane), 32 edges/block in flight,
//            epay prefetch pipelined across blocks; + MLP + readout ----------
__global__ void agg2_node2_kernel(const __half* __restrict__ h1,
                                  const int* __restrict__ starts,
                                  const int* __restrict__ deg,
                                  const int2* __restrict__ epay,
                                  const float* __restrict__ e2w,
                                  const float* __restrict__ e2b,
                                  const float* __restrict__ w2aT,
                                  const float* __restrict__ b2a,
                                  const float* __restrict__ w2bT,
                                  const float* __restrict__ b2b,
                                  const float* __restrict__ wr1T,
                                  const float* __restrict__ br1,
                                  const float* __restrict__ wr2,
                                  const float* __restrict__ br2,
                                  const int* __restrict__ term,
                                  const float* __restrict__ ccost,
                                  const int* __restrict__ batch,
                                  float* __restrict__ pi,
                                  float* __restrict__ te) {
    int n = blockIdx.x * (blockDim.x >> 6) + (threadIdx.x >> 6);
    int f = threadIdx.x & 63;
    if (n >= N_NODES) return;
    int q = f >> 4;          // edge slot 0..3 within a gather round
    int t4 = f & 15;         // feature quad: features 4*t4 .. 4*t4+3
    int s0 = starts[n], dg = deg[n];
    const int2* ep = epay + s0;
    float w0 = e2w[4 * t4], w1 = e2w[4 * t4 + 1], w2 = e2w[4 * t4 + 2], w3 = e2w[4 * t4 + 3];
    float b0 = e2b[4 * t4], b1 = e2b[4 * t4 + 1], b2 = e2b[4 * t4 + 2], b3 = e2b[4 * t4 + 3];
    float acc0 = 0.f, acc1 = 0.f, acc2 = 0.f, acc3 = 0.f;

#define CONSUME(AV, RV) do {                                                \
        __half2 h01_ = *(__half2*)&(RV).x;                                  \
        __half2 h23_ = *(__half2*)&(RV).y;                                  \
        float2 f01_ = __half22float2(h01_);                                 \
        float2 f23_ = __half22float2(h23_);                                 \
        acc0 += fmaxf(f01_.x + (AV) * w0 + b0, 0.f);                        \
        acc1 += fmaxf(f01_.y + (AV) * w1 + b1, 0.f);                        \
        acc2 += fmaxf(f23_.x + (AV) * w2 + b2, 0.f);                        \
        acc3 += fmaxf(f23_.y + (AV) * w3 + b3, 0.f);                        \
    } while (0)

    int nblk = dg >> 5;      // full 32-edge blocks
    if (nblk > 0) {
        int2 p0 = ep[0 + q],  p1 = ep[4 + q],  p2 = ep[8 + q],  p3 = ep[12 + q];
        int2 p4 = ep[16 + q], p5 = ep[20 + q], p6 = ep[24 + q], p7 = ep[28 + q];
        for (int b = 0; b < nblk; ++b) {
            // gathers for current block (32 edges in flight)
            float2 r0 = *(const float2*)(h1 + p0.x * H + 4 * t4);
            float2 r1 = *(const float2*)(h1 + p1.x * H + 4 * t4);
            float2 r2 = *(const float2*)(h1 + p2.x * H + 4 * t4);
            float2 r3 = *(const float2*)(h1 + p3.x * H + 4 * t4);
            float2 r4 = *(const float2*)(h1 + p4.x * H + 4 * t4);
            float2 r5 = *(const float2*)(h1 + p5.x * H + 4 * t4);
            float2 r6 = *(const float2*)(h1 + p6.x * H + 4 * t4);
            float2 r7 = *(const float2*)(h1 + p7.x * H + 4 * t4);
            float a0 = __int_as_float(p0.y), a1v = __int_as_float(p1.y);
            float a2v = __int_as_float(p2.y), a3 = __int_as_float(p3.y);
            float a4 = __int_as_float(p4.y), a5 = __int_as_float(p5.y);
            float a6 = __int_as_float(p6.y), a7 = __int_as_float(p7.y);
            // prefetch next block's payloads while gathers are in flight
            int jn = ((b + 1 < nblk) ? (b + 1) : b) << 5;
            p0 = ep[jn + 0 + q];  p1 = ep[jn + 4 + q];
            p2 = ep[jn + 8 + q];  p3 = ep[jn + 12 + q];
            p4 = ep[jn + 16 + q]; p5 = ep[jn + 20 + q];
            p6 = ep[jn + 24 + q]; p7 = ep[jn + 28 + q];
            CONSUME(a0, r0); CONSUME(a1v, r1); CONSUME(a2v, r2); CONSUME(a3, r3);
            CONSUME(a4, r4); CONSUME(a5, r5); CONSUME(a6, r6); CONSUME(a7, r7);
        }
    }
    int j = nblk << 5;
    for (; j + 4 <= dg; j += 4) {
        int2 p = ep[j + q];
        float2 r = *(const float2*)(h1 + p.x * H + 4 * t4);
        float a = __int_as_float(p.y);
        CONSUME(a, r);
    }
    if (j < dg && q < dg - j) {     // 1..3 leftover edges
        int2 p = ep[j + q];
        float2 r = *(const float2*)(h1 + p.x * H + 4 * t4);
        float a = __int_as_float(p.y);
        CONSUME(a, r);
    }
#undef CONSUME
    // reduce the 4 slots
    acc0 += __shfl_xor(acc0, 16, 64); acc0 += __shfl_xor(acc0, 32, 64);
    acc1 += __shfl_xor(acc1, 16, 64); acc1 += __shfl_xor(acc1, 32, 64);
    acc2 += __shfl_xor(acc2, 16, 64); acc2 += __shfl_xor(acc2, 32, 64);
    acc3 += __shfl_xor(acc3, 16, 64); acc3 += __shfl_xor(acc3, 32, 64);
    // redistribute: lane f wants feature f = 4*(f>>2) + (f&3), held by lane (f>>2)
    int srcl = f >> 2;
    float c0 = __shfl(acc0, srcl, 64);
    float c1 = __shfl(acc1, srcl, 64);
    float c2 = __shfl(acc2, srcl, 64);
    float c3 = __shfl(acc3, srcl, 64);
    float aggf = (f & 2) ? ((f & 1) ? c3 : c2) : ((f & 1) ? c1 : c0);

    float h = __half2float(h1[n * H + f]) + aggf;
    float m1 = b2a[f];
#pragma unroll 16
    for (int k = 0; k < H; ++k)
        m1 += __shfl(h, k, 64) * w2aT[k * H + f];
    float h2a = fmaxf(m1, 0.f);
    float m2 = b2b[f];
#pragma unroll 16
    for (int k = 0; k < H; ++k)
        m2 += __shfl(h2a, k, 64) * w2bT[k * H + f];
    float h2 = fmaxf(m2, 0.f);
    int fr = f & 31;
    float accr = br1[fr];
#pragma unroll 16
    for (int k = 0; k < H; ++k)
        accr += __shfl(h2, k, 64) * wr1T[k * 32 + fr];
    float r = fmaxf(accr, 0.f);
    float val = (f < 32) ? r * wr2[fr] : 0.f;
#pragma unroll
    for (int off = 32; off > 0; off >>= 1)
        val += __shfl_xor(val, off, 64);
    if (f == 0) {
        float z = val + br2[0];
        float sig = 1.f / (1.f + expf(-z));
        float p = sig * (1.f - (float)term[n]);
        pi[n] = p;
        atomicAdd(&te[batch[n]], p * ccost[n]);
    }
}

__global__ void final_kernel(const float* __restrict__ pi,
                             const int* __restrict__ batch,
                             const float* __restrict__ Btot,
                             const float* __restrict__ te,
                             float* __restrict__ out) {
    int n = blockIdx.x * blockDim.x + threadIdx.x;
    if (n >= N_NODES) return;
    int b = batch[n];
    float ratio = fminf(Btot[b] / (te[b] + 1e-12f), 1.f);
    out[n] = pi[n] * ratio;
}

extern "C" void kernel_launch(void* const* d_in, const int* in_sizes, int n_in,
                              void* d_out, int out_size, void* d_ws, size_t ws_size,
                              hipStream_t stream) {
    const float* x     = (const float*)d_in[0];
    const int*   ei    = (const int*)d_in[1];
    const float* ea    = (const float*)d_in[2];
    const int*   batch = (const int*)d_in[3];
    const float* Btot  = (const float*)d_in[4];
    const int*   term  = (const int*)d_in[5];
    const float* ccost = (const float*)d_in[6];
    const float* e1w   = (const float*)d_in[7];
    const float* e1b   = (const float*)d_in[8];
    const float* w1a   = (const float*)d_in[9];
    const float* b1a   = (const float*)d_in[10];
    const float* w1b   = (const float*)d_in[11];
    const float* b1b   = (const float*)d_in[12];
    const float* e2w   = (const float*)d_in[13];
    const float* e2b   = (const float*)d_in[14];
    const float* w2a   = (const float*)d_in[15];
    const float* b2a   = (const float*)d_in[16];
    const float* w2b   = (const float*)d_in[17];
    const float* b2b   = (const float*)d_in[18];
    const float* wr1   = (const float*)d_in[19];
    const float* br1   = (const float*)d_in[20];
    const float* wr2   = (const float*)d_in[21];
    const float* br2   = (const float*)d_in[22];

    char* p = (char*)d_ws;
    int*    deg    = (int*)p;    p += sizeof(int)    * N_NODES;   // zeroed
    float*  te     = (float*)p;  p += sizeof(float)  * N_GRAPHS;  // zeroed
    int*    starts = (int*)p;    p += sizeof(int)    * N_NODES;
    int*    next   = (int*)p;    p += sizeof(int)    * N_NODES;
    int*    csum   = (int*)p;    p += sizeof(int)    * 64;
    int*    coff   = (int*)p;    p += sizeof(int)    * 64;
    int2*   epay   = (int2*)p;   p += sizeof(int2)   * (size_t)N_EDGES;
    __half* h1     = (__half*)p; p += sizeof(__half) * (size_t)N_NODES * H;
    float*  pi     = (float*)p;  p += sizeof(float)  * N_NODES;
    float*  w1aT   = (float*)p;  p += sizeof(float)  * F_IN * H;
    float*  w1bT   = (float*)p;  p += sizeof(float)  * H * H;
    float*  w2aT   = (float*)p;  p += sizeof(float)  * H * H;
    float*  w2bT   = (float*)p;  p += sizeof(float)  * H * H;
    float*  wr1T   = (float*)p;  p += sizeof(float)  * H * 32;
    float*  out    = (float*)d_out;

    hipMemsetAsync(d_ws, 0, sizeof(int) * N_NODES + sizeof(float) * N_GRAPHS, stream);

    prep_kernel<<<1 + (N_EDGES / 4 + 255) / 256, 256, 0, stream>>>(
        ei, deg, w1a, w1b, w2a, w2b, wr1, w1aT, w1bT, w2aT, w2bT, wr1T);
    scan_local<<<N_CHUNKS, SCAN_BLOCK, 0, stream>>>(deg, starts, csum);
    scan_top<<<1, 64, 0, stream>>>(csum, coff);
    scan_add<<<N_CHUNKS, SCAN_BLOCK, 0, stream>>>(starts, next, coff);
    scatter_kernel<<<(N_EDGES + 255) / 256, 256, 0, stream>>>(ei, ea, next, epay);
    conv1_kernel<<<(N_NODES + 3) / 4, 256, 0, stream>>>(x, starts, deg, epay,
                                                        e1w, e1b, w1aT, b1a, w1bT, b1b, h1);
    agg2_node2_kernel<<<(N_NODES + 3) / 4, 256, 0, stream>>>(h1, starts, deg, epay,
                                                             e2w, e2b, w2aT, b2a, w2bT, b2b,
                                                             wr1T, br1, wr2, br2,
                                                             term, ccost, batch, pi, te);
    final_kernel<<<(N_NODES + 255) / 256, 256, 0, stream>>>(pi, batch, Btot, te, out);
}